// Round 14
// baseline (199.317 us; speedup 1.0000x reference)
//
#include <hip/hip_runtime.h>
#include <stdint.h>

// pairs_of_pairs: fused [concat -> conv1x1+relu x3]
// B=32, C=64, S=64, CC=128, OC=256. 2016 rows of 64 positions.
// R13: PERSISTENT blocks. Evidence: pipes sum to ~90us serial ~= 118 observed
// (barrier-lockstep => one pipe hot at a time); 1 block/CU means block n+1's
// build waits for block n's exit. R2 proved co-residency alone doesn't help.
// Fix: grid 252, each block runs 4 row-units; next unit's 48 build loads are
// issued DURING layer-2's store phase (T14 split: load->regs early, ds_write
// after the X-dead barrier) so build latency vanishes; epilogue = DIRECT
// global_store_dword (reg v spans 16 consecutive pos across l16 = 64B
// contiguous per 16-lane group) - no bounce, no extra barriers.
// Kept (R11): 2-row units (b0,b0+16), 8 waves x 32o x 128pos, xaddr swizzle,
// rolled chunk aliased from chunk2, 2 A-loads : 16 MFMA per kk.

typedef __attribute__((ext_vector_type(8))) __bf16 bf16x8;
typedef __attribute__((ext_vector_type(4))) float f32x4;
typedef __attribute__((ext_vector_type(4))) unsigned short u16x4;
typedef __attribute__((ext_vector_type(8))) unsigned short u16x8;

__device__ __forceinline__ unsigned short f2bf(float f) {
  unsigned int u = __builtin_bit_cast(unsigned int, f);
  u += 0x7FFFu + ((u >> 16) & 1u);
  return (unsigned short)(u >> 16);
}

// X: 4 chunk regions of [128 pos][64 ch] bf16 (8192 elems each).
// Within chunk: 16B-slot = pos*8 + ((c6/8) ^ (pos&7)) -> max 2-way (free).
__device__ __forceinline__ int xaddr(int pos, int c) {
  int slot = (pos << 3) + ((((c & 63) >> 3) ^ pos) & 7);
  return ((c >> 6) << 13) + (slot << 3) + (c & 7);
}

__global__ void wconv_kernel(const float* __restrict__ W1, const float* __restrict__ W2,
                             const float* __restrict__ W3, unsigned short* __restrict__ wb) {
  int i = (blockIdx.x * 256 + threadIdx.x) * 4;  // grid 64 -> 65536 per layer
  const float* Ws[3] = {W1, W2, W3};
#pragma unroll
  for (int L = 0; L < 3; ++L) {
    f32x4 a = *(const f32x4*)(Ws[L] + i);
    u16x4 p;
#pragma unroll
    for (int v = 0; v < 4; ++v) p[v] = f2bf(a[v]);
    *(u16x4*)(wb + L * 65536 + i) = p;
  }
}

__global__ __launch_bounds__(512, 1)
void fused_kernel(const float* __restrict__ x, const float* __restrict__ xc,
                  const unsigned short* __restrict__ wb,
                  const float* __restrict__ b1, const float* __restrict__ b2,
                  const float* __restrict__ b3, float* __restrict__ out) {
  __shared__ __align__(16) unsigned char lraw[65536];
  unsigned short* X = (unsigned short*)lraw;   // 64KB, 4 chunk regions

  const int tid = threadIdx.x;    // 0..511
  const int lane = tid & 63;
  const int g16 = lane >> 4;
  const int l16 = lane & 15;
  const int wv = tid >> 6;        // wave 0..7
  const int ow = wv * 32;
  const int p = tid & 63;         // build: position owned by this thread
  const int c0 = (tid >> 6) << 3; // build: c-octet 0,8,...,56

  const int unit0 = blockIdx.x * 4;   // 252 blocks x 4 units = 1008

  // next-unit staging registers: 6 chunk-rows x 8 floats = 48 VGPR
  float xr[6][8];
  auto ldunit = [&](int u) {          // issue 48 coalesced global loads
    int bb = u / 63, de = u % 63;
#pragma unroll
    for (int cr = 0; cr < 6; ++cr) {
      int rr = cr / 3, ck = cr - rr * 3;
      int b = bb + 16 * rr;
#pragma unroll
      for (int j = 0; j < 8; ++j)
        xr[cr][j] = (ck < 2) ? xc[(((b * 128 + ck * 64 + c0 + j) * 63) + de) * 64 + p]
                             : x[(b * 64 + c0 + j) * 64 + p];
    }
  };
  auto wrunit = [&]() {               // xr -> X (6 swizzled ds_write_b128)
#pragma unroll
    for (int cr = 0; cr < 6; ++cr) {
      int rr = cr / 3, ck = cr - rr * 3;
      u16x8 v;
#pragma unroll
      for (int j = 0; j < 8; ++j) v[j] = f2bf(xr[cr][j]);
      *(u16x8*)&X[xaddr(rr * 64 + p, ck * 64 + c0)] = v;
    }
  };

  // prologue: build unit0's X
  ldunit(unit0);
  wrunit();
  __syncthreads();

#pragma unroll 1
  for (int i = 0; i < 4; ++i) {
    const int unit = unit0 + i;
    const int b0 = unit / 63;
    const int dd = unit % 63;
    const int d = dd + 1;

#pragma unroll 1
    for (int layer = 0; layer < 3; ++layer) {
      const unsigned short* wl = wb + layer * 65536;
      const float* bias = (layer == 0) ? b1 : (layer == 1) ? b2 : b3;
      const bool al3 = (layer == 0);   // layer-0 k>=192 aliases chunk2 shifted

      f32x4 acc[2][8] = {};            // [mf][nf], wave tile = 32 o x 128 pos

#pragma unroll
      for (int kk = 0; kk < 8; ++kk) {
        int kb = kk * 32 + g16 * 8;    // lane-group's k-base
        bool a3 = al3 && (kk >= 6);
        int cc = a3 ? (128 + (kb & 63)) : kb;  // rolled -> chunk2 region
        bf16x8 afr[2];
#pragma unroll
        for (int mf = 0; mf < 2; ++mf)
          afr[mf] = __builtin_bit_cast(
              bf16x8, *(const u16x8*)(wl + (ow + mf * 16 + l16) * 256 + kb));
        bf16x8 bfr[4];
#pragma unroll
        for (int nf = 0; nf < 4; ++nf) {   // row0 positions 0..63
          int ii = nf * 16 + l16;
          int ie = a3 ? ((ii - d) & 63) : ii;
          bfr[nf] = __builtin_bit_cast(bf16x8, *(const u16x8*)&X[xaddr(ie, cc)]);
        }
#pragma unroll
        for (int mf = 0; mf < 2; ++mf)
#pragma unroll
          for (int nf = 0; nf < 4; ++nf)
            acc[mf][nf] = __builtin_amdgcn_mfma_f32_16x16x32_bf16(afr[mf], bfr[nf], acc[mf][nf], 0, 0, 0);
#pragma unroll
        for (int nf = 0; nf < 4; ++nf) {   // row1 positions 64..127
          int ii = nf * 16 + l16;
          int ie = 64 + (a3 ? ((ii - d) & 63) : ii);
          bfr[nf] = __builtin_bit_cast(bf16x8, *(const u16x8*)&X[xaddr(ie, cc)]);
        }
#pragma unroll
        for (int mf = 0; mf < 2; ++mf)
#pragma unroll
          for (int nf = 0; nf < 4; ++nf)
            acc[mf][4 + nf] = __builtin_amdgcn_mfma_f32_16x16x32_bf16(afr[mf], bfr[nf], acc[mf][4 + nf], 0, 0, 0);
      }

      if (layer < 2) {
        __syncthreads();  // all waves done reading X
        // bias + relu -> bf16 back into X (D frag: pos=l16 col, o=g16*4+v)
#pragma unroll
        for (int mf = 0; mf < 2; ++mf) {
          int o0 = ow + mf * 16 + g16 * 4;
          f32x4 bv = *(const f32x4*)(bias + o0);
#pragma unroll
          for (int nf = 0; nf < 8; ++nf) {
            int pos = nf * 16 + l16;   // 0..127 covers both rows
            u16x4 pk;
#pragma unroll
            for (int v = 0; v < 4; ++v)
              pk[v] = f2bf(fmaxf(acc[mf][nf][v] + bv[v], 0.f));
            *(u16x4*)&X[xaddr(pos, o0)] = pk;
          }
        }
        __syncthreads();
      } else {
        // ---- layer 2 epilogue: prefetch next unit, direct stores ----
        if (i < 3) ldunit(unit + 1);   // loads in flight under the stores

        // direct global stores: for reg v, lanes l16=0..15 write 16
        // consecutive pos at fixed o -> 64B contiguous per 16-lane group.
#pragma unroll
        for (int rr = 0; rr < 2; ++rr) {
          const int bq = b0 + 16 * rr;
#pragma unroll
          for (int mf = 0; mf < 2; ++mf) {
            int o0 = ow + mf * 16 + g16 * 4;
            f32x4 bv = *(const f32x4*)(bias + o0);
#pragma unroll
            for (int nf = 0; nf < 4; ++nf) {
              int pos = nf * 16 + l16;
#pragma unroll
              for (int v = 0; v < 4; ++v)
                out[(((bq * 256 + o0 + v) * 63) + dd) * 64 + pos] =
                    fmaxf(acc[mf][rr * 4 + nf][v] + bv[v], 0.f);
            }
          }
        }

        if (i < 3) {
          __syncthreads();   // X dead for all waves (layer-2 reads complete)
          wrunit();          // write next unit's X (waits on xr loads)
          __syncthreads();   // X ready for next iteration's layer 0
        }
      }
    }
  }
}

extern "C" void kernel_launch(void* const* d_in, const int* in_sizes, int n_in,
                              void* d_out, int out_size, void* d_ws, size_t ws_size,
                              hipStream_t stream) {
  const float* x  = (const float*)d_in[0];
  const float* xc = (const float*)d_in[1];
  const float* W1 = (const float*)d_in[2];
  const float* b1 = (const float*)d_in[3];
  const float* W2 = (const float*)d_in[4];
  const float* b2 = (const float*)d_in[5];
  const float* W3 = (const float*)d_in[6];
  const float* b3 = (const float*)d_in[7];
  float* out = (float*)d_out;
  unsigned short* wb = (unsigned short*)d_ws;  // 3 x 256 x 256 bf16 = 384 KB

  wconv_kernel<<<64, 256, 0, stream>>>(W1, W2, W3, wb);
  fused_kernel<<<252, 512, 0, stream>>>(x, xc, wb, b1, b2, b3, out);
}

// Round 15
// 157.337 us; speedup vs baseline: 1.2668x; 1.2668x over previous
//
#include <hip/hip_runtime.h>
#include <stdint.h>

// pairs_of_pairs: fused [concat -> conv1x1+relu x3]
// B=32, C=64, S=64, CC=128, OC=256. 2016 rows of 64 positions.
// R14: persistent blocks + DOUBLE-BUFFERED X (2x32KB), 1-row units.
// R13 failed on register spill (48-reg staging live across the epilogue ->
// 280MB scratch). Here: 8 units/block (grid 252), unit i computes from
// buf[i&1] while unit i+1's 24 build loads (xr[3][8]=24 VGPR, short-lived)
// issue at layer-1 start and ds_write to buf[~i&1] right after layer-1's kk.
// No global latency inside any barrier wait; 4 lgkm-only barriers/unit.
// Layer-2: direct 64B-segment global stores (no bounce), drain under next
// unit. Unit layout (R12, proven): X chunks [64pos][64ch] swizzled, rolled
// chunk aliased from chunk2 at shifted pos; h overwrites the same 32KB buf
// as [64pos][256ch]. Wave = 32o x 64pos, acc[2][4]=32 AGPR, 2 A-loads:8 MFMA.

typedef __attribute__((ext_vector_type(8))) __bf16 bf16x8;
typedef __attribute__((ext_vector_type(4))) float f32x4;
typedef __attribute__((ext_vector_type(4))) unsigned short u16x4;
typedef __attribute__((ext_vector_type(8))) unsigned short u16x8;

__device__ __forceinline__ unsigned short f2bf(float f) {
  unsigned int u = __builtin_bit_cast(unsigned int, f);
  u += 0x7FFFu + ((u >> 16) & 1u);
  return (unsigned short)(u >> 16);
}

// chunk layout within a 32KB buffer: chunk ck base = ck*4096 elems;
// [64 pos][64 ch] swizzled: 16B-slot = p*8 + ((c6>>3)^p)&7 -> ~2-way max.
__device__ __forceinline__ int xa(int ck, int p, int c6) {
  return ck * 4096 + (p * 8 + (((c6 >> 3) ^ p) & 7)) * 8 + (c6 & 7);
}
// h layout (layers 1-2 input): [64 pos][256 ch]: 16B-slot = p*32 + ((c>>3)^p)&31.
__device__ __forceinline__ int xh(int p, int c) {
  return (p * 32 + (((c >> 3) ^ p) & 31)) * 8 + (c & 7);
}

__global__ void wconv_kernel(const float* __restrict__ W1, const float* __restrict__ W2,
                             const float* __restrict__ W3, unsigned short* __restrict__ wb) {
  int i = (blockIdx.x * 256 + threadIdx.x) * 4;  // grid 64 -> 65536 per layer
  const float* Ws[3] = {W1, W2, W3};
#pragma unroll
  for (int L = 0; L < 3; ++L) {
    f32x4 a = *(const f32x4*)(Ws[L] + i);
    u16x4 p;
#pragma unroll
    for (int v = 0; v < 4; ++v) p[v] = f2bf(a[v]);
    *(u16x4*)(wb + L * 65536 + i) = p;
  }
}

__global__ __launch_bounds__(512, 2)
void fused_kernel(const float* __restrict__ x, const float* __restrict__ xc,
                  const unsigned short* __restrict__ wb,
                  const float* __restrict__ b1, const float* __restrict__ b2,
                  const float* __restrict__ b3, float* __restrict__ out) {
  __shared__ __align__(16) unsigned char lraw[65536];   // 2 x 32KB X buffers

  const int tid = threadIdx.x;    // 0..511
  const int lane = tid & 63;
  const int g16 = lane >> 4;
  const int l16 = lane & 15;
  const int wv = tid >> 6;        // wave 0..7, owns o in [wv*32, wv*32+32)
  const int ow = wv * 32;
  const int p = tid & 63;         // build: position owned by this thread
  const int c0 = (tid >> 6) << 3; // build: c-octet 0,8,...,56

  const int unit0 = blockIdx.x * 8;   // 252 blocks x 8 units = 2016 rows

  // short-lived staging: 3 chunks x 8 floats = 24 VGPR (R13 had 48, spilled)
  float xr[3][8];
  auto ldunit = [&](int u) {          // issue 24 coalesced global loads
    int bb = u / 63, de = u % 63;
#pragma unroll
    for (int ck = 0; ck < 3; ++ck)
#pragma unroll
      for (int j = 0; j < 8; ++j)
        xr[ck][j] = (ck < 2) ? xc[(((bb * 128 + ck * 64 + c0 + j) * 63) + de) * 64 + p]
                             : x[(bb * 64 + c0 + j) * 64 + p];
  };
  auto wrunit = [&](unsigned short* Xt) {  // xr -> Xt (3 swizzled ds_write_b128)
#pragma unroll
    for (int ck = 0; ck < 3; ++ck) {
      u16x8 v;
#pragma unroll
      for (int j = 0; j < 8; ++j) v[j] = f2bf(xr[ck][j]);
      *(u16x8*)&Xt[xa(ck, p, c0)] = v;
    }
  };

  // prologue: build unit0 into buf0
  ldunit(unit0);
  wrunit((unsigned short*)lraw);
  __syncthreads();

#pragma unroll 1
  for (int i = 0; i < 8; ++i) {
    const int unit = unit0 + i;
    const int b = unit / 63;
    const int dd = unit % 63;
    const int d = dd + 1;
    unsigned short* Xc = (unsigned short*)(lraw + ((i & 1) << 15));      // current
    unsigned short* Xo = (unsigned short*)(lraw + ((~i & 1) << 15));     // next

#pragma unroll 1
    for (int layer = 0; layer < 3; ++layer) {
      const unsigned short* wl = wb + layer * 65536;
      const float* bias = (layer == 0) ? b1 : (layer == 1) ? b2 : b3;
      const bool al3 = (layer == 0);   // layer-0 k>=192 aliases chunk2 shifted

      // issue next unit's build loads early: they arrive during this kk loop
      if (layer == 1 && i < 7) ldunit(unit + 1);

      f32x4 acc[2][4] = {};            // [mf][nf], wave tile = 32 o x 64 pos

#pragma unroll
      for (int kk = 0; kk < 8; ++kk) {
        int kb = kk * 32 + g16 * 8;    // lane-group's 8-wide k-base
        bf16x8 afr[2];
#pragma unroll
        for (int mf = 0; mf < 2; ++mf)
          afr[mf] = __builtin_bit_cast(
              bf16x8, *(const u16x8*)(wl + (ow + mf * 16 + l16) * 256 + kb));
        bf16x8 bfr[4];
#pragma unroll
        for (int nf = 0; nf < 4; ++nf) {
          int pp = nf * 16 + l16;      // position
          int addr;
          if (layer > 0)    addr = xh(pp, kb);
          else if (kk < 2)  addr = xa(0, pp, kb);
          else if (kk < 4)  addr = xa(1, pp, kb - 64);
          else if (kk < 6)  addr = xa(2, pp, kb - 128);
          else              addr = xa(2, (pp - d) & 63, kb - 192);  // rolled x
          bfr[nf] = __builtin_bit_cast(bf16x8, *(const u16x8*)&Xc[addr]);
        }
#pragma unroll
        for (int mf = 0; mf < 2; ++mf)
#pragma unroll
          for (int nf = 0; nf < 4; ++nf)
            acc[mf][nf] = __builtin_amdgcn_mfma_f32_16x16x32_bf16(afr[mf], bfr[nf], acc[mf][nf], 0, 0, 0);
      }

      // write next unit's X into the OTHER buffer (no race: different buf;
      // visibility to all waves via the barrier below)
      if (layer == 1 && i < 7) wrunit(Xo);

      if (layer < 2) {
        __syncthreads();  // all waves done reading Xc this phase
        // bias + relu -> bf16 h into Xc (D frag: pos=l16 col, o=g16*4+v row)
#pragma unroll
        for (int mf = 0; mf < 2; ++mf) {
          int o0 = ow + mf * 16 + g16 * 4;
          f32x4 bv = *(const f32x4*)(bias + o0);
#pragma unroll
          for (int nf = 0; nf < 4; ++nf) {
            int pos = nf * 16 + l16;
            u16x4 pk;
#pragma unroll
            for (int v = 0; v < 4; ++v)
              pk[v] = f2bf(fmaxf(acc[mf][nf][v] + bv[v], 0.f));
            *(u16x4*)&Xc[xh(pos, o0)] = pk;
          }
        }
        __syncthreads();
      } else {
        // layer 2: bias+relu -> direct global stores (64B per 16-lane group);
        // stores drain under the next unit's compute. No barrier here: the
        // next unit's first LDS write to Xc happens after its own bar1, which
        // laggards reach only after finishing these reads of Xc.
#pragma unroll
        for (int mf = 0; mf < 2; ++mf) {
          int o0 = ow + mf * 16 + g16 * 4;
          f32x4 bv = *(const f32x4*)(bias + o0);
#pragma unroll
          for (int nf = 0; nf < 4; ++nf) {
            int pos = nf * 16 + l16;
#pragma unroll
            for (int v = 0; v < 4; ++v)
              out[(((b * 256 + o0 + v) * 63) + dd) * 64 + pos] =
                  fmaxf(acc[mf][nf][v] + bv[v], 0.f);
          }
        }
      }
    }
  }
}

extern "C" void kernel_launch(void* const* d_in, const int* in_sizes, int n_in,
                              void* d_out, int out_size, void* d_ws, size_t ws_size,
                              hipStream_t stream) {
  const float* x  = (const float*)d_in[0];
  const float* xc = (const float*)d_in[1];
  const float* W1 = (const float*)d_in[2];
  const float* b1 = (const float*)d_in[3];
  const float* W2 = (const float*)d_in[4];
  const float* b2 = (const float*)d_in[5];
  const float* W3 = (const float*)d_in[6];
  const float* b3 = (const float*)d_in[7];
  float* out = (float*)d_out;
  unsigned short* wb = (unsigned short*)d_ws;  // 3 x 256 x 256 bf16 = 384 KB

  wconv_kernel<<<64, 256, 0, stream>>>(W1, W2, W3, wb);
  fused_kernel<<<252, 512, 0, stream>>>(x, xc, wb, b1, b2, b3, out);
}